// Round 2
// baseline (414.397 us; speedup 1.0000x reference)
//
#include <hip/hip_runtime.h>

typedef unsigned int uint32;
typedef unsigned short u16;
typedef float fx4 __attribute__((ext_vector_type(4)));
typedef uint32 u32x4 __attribute__((ext_vector_type(4)));

typedef const __attribute__((address_space(1))) void gvoid;
typedef __attribute__((address_space(3))) void lvoid;

#define MFMA_BF16_16x16x32(acc, a, b) \
  asm("v_mfma_f32_16x16x32_bf16 %0, %1, %2, %0" : "+v"(acc) : "v"(a), "v"(b))

__device__ __forceinline__ u16 f2bf_rne(float f) {
  uint32 u = __builtin_bit_cast(uint32, f);
  u += 0x7FFFu + ((u >> 16) & 1u);
  return (u16)(u >> 16);
}

__device__ __forceinline__ uint32 cvt_pk_bf16(float lo, float hi) {
  uint32 r;
  asm("v_cvt_pk_bf16_f32 %0, %1, %2" : "=v"(r) : "v"(lo), "v"(hi));
  return r;
}

// ---------------------------------------------------------------------------
// K2: x (fp32) -> bf16. 2048 blocks x 256 threads x float4 = 2^21 elems
// ---------------------------------------------------------------------------
__global__ __launch_bounds__(256) void cvtx_kernel(const float* __restrict__ x,
                                                   u16* __restrict__ xb) {
  const int i = blockIdx.x * 256 + threadIdx.x;
  float4 v = ((const float4*)x)[i];
  ushort4 o;
  o.x = f2bf_rne(v.x);
  o.y = f2bf_rne(v.y);
  o.z = f2bf_rne(v.z);
  o.w = f2bf_rne(v.w);
  ((ushort4*)xb)[i] = o;
}

// ---------------------------------------------------------------------------
// decode body: dec[t,r,d] = scales[t]*0.25 * sum_k cw[idx[t,r,k], d] (bf16)
// runs as the 256-block prefix of the fused kernel; 16 rows per block
// ---------------------------------------------------------------------------
__device__ __forceinline__ void decode_body(
    int bid, const float* __restrict__ cw, const int* __restrict__ indices,
    const float* __restrict__ scales, u16* __restrict__ dec) {
  const int tid = threadIdx.x;
#pragma unroll 1
  for (int rr = 0; rr < 16; ++rr) {
    const int row = bid * 16 + rr;       // t*512 + r
    const int t = row >> 9;
    const int* ip = indices + (size_t)row * 4;
    const float* c0 = cw + (size_t)ip[0] * 4096;
    const float* c1 = cw + (size_t)ip[1] * 4096;
    const float* c2 = cw + (size_t)ip[2] * 4096;
    const float* c3 = cw + (size_t)ip[3] * 4096;
    const float s = scales[t] * 0.25f;
    u16* orow = dec + (size_t)row * 4096;
#pragma unroll
    for (int j = 0; j < 4; ++j) {
      const int d = j * 1024 + tid * 4;
      float4 a = *(const float4*)(c0 + d);
      float4 b = *(const float4*)(c1 + d);
      float4 c = *(const float4*)(c2 + d);
      float4 e = *(const float4*)(c3 + d);
      ushort4 o;
      o.x = f2bf_rne((a.x + b.x + c.x + e.x) * s);
      o.y = f2bf_rne((a.y + b.y + c.y + e.y) * s);
      o.z = f2bf_rne((a.z + b.z + c.z + e.z) * s);
      o.w = f2bf_rne((a.w + b.w + c.w + e.w) * s);
      *(ushort4*)(orow + d) = o;
    }
  }
}

// ---------------------------------------------------------------------------
// Fused kernel: blocks [0,256)   = decode (memory-bound, overlaps)
//               blocks [256,1280)= z[t] = x_bf16 @ rot[t]^T
// GEMM: M=512, N=4096, K=4096 per tile; 128x128 tile, BK=32, 4 waves.
// A (bf16) staged via global_load_lds. B (fp32 rot) reg-staged:
// global_load_dwordx4 -> v_cvt_pk_bf16_f32 -> ds_write_b128, so LDS holds
// bf16 and the inner loop is the m97 shape (8 ds_read_b128 + 16 MFMA).
// Next K-step's B loads issue right after barrier #1 (latency under MFMA).
// ---------------------------------------------------------------------------
__global__ __launch_bounds__(256, 2) void fused_z_decode_kernel(
    const u16* __restrict__ Xb,    // [512][4096] bf16
    const float* __restrict__ rot, // [8][4096][4096] fp32
    u16* __restrict__ Z,           // [8][512][4096] bf16
    const float* __restrict__ cw, const int* __restrict__ indices,
    const float* __restrict__ scales, u16* __restrict__ dec) {
  __shared__ char sA[8192];       // 128 x 32 bf16
  __shared__ char sB[8192];       // 128 x 32 bf16 (packed from fp32)

  const int bid = blockIdx.x;
  if (bid < 256) {
    decode_body(bid, cw, indices, scales, dec);
    return;
  }
  const int lb = bid - 256;
  const int swz = ((lb & 7) << 7) | (lb >> 3);  // XCD-chunked (1024 % 8 == 0)
  const int t = swz >> 7;
  const int rem = swz & 127;
  const int nb = rem >> 2, mb = rem & 3;        // B-panel sharers adjacent
  const float* Bt = rot + ((size_t)t << 24);
  u16* Ct = Z + ((size_t)t << 21);
  const int aRow0 = mb << 7, bCol0 = nb << 7;
  const int tid = threadIdx.x;
  const int wv = tid >> 6, ln = tid & 63;
  const int lr = ln & 15, lk = ln >> 4;
  const int wr = wv >> 1, wc = wv & 1;

  fx4 acc[4][4] = {};

  // A staging map (global_load_lds, linear)
  const int rowA_l = ln >> 2;
  const int kkA = (ln & 3) * 8;

  // B staging map (reg path): thread -> row tid>>1, k-half (tid&1)*16 fp32
  const float* bsrc0 = Bt + (size_t)(bCol0 + (tid >> 1)) * 4096 + (tid & 1) * 16;
  const int bldsoff = (tid >> 1) * 64 + (tid & 1) * 32;

  float4 br0, br1, br2, br3;
  br0 = *(const float4*)(bsrc0 + 0);
  br1 = *(const float4*)(bsrc0 + 4);
  br2 = *(const float4*)(bsrc0 + 8);
  br3 = *(const float4*)(bsrc0 + 12);

  for (int k0 = 0; k0 < 4096; k0 += 32) {
    // ---- A tile async into LDS (8 KB) ----
#pragma unroll
    for (int c = 0; c < 2; ++c) {
      const int seg = wv * 2 + c;
      const int row = seg * 16 + rowA_l;
      __builtin_amdgcn_global_load_lds(
          (gvoid*)(Xb + (size_t)(aRow0 + row) * 4096 + (k0 + kkA)),
          (lvoid*)(sA + seg * 1024 + ln * 16), 16, 0, 0);
    }
    // ---- pack this K-step's B regs -> bf16 LDS ----
    u32x4 p0, p1;
    p0[0] = cvt_pk_bf16(br0.x, br0.y);
    p0[1] = cvt_pk_bf16(br0.z, br0.w);
    p0[2] = cvt_pk_bf16(br1.x, br1.y);
    p0[3] = cvt_pk_bf16(br1.z, br1.w);
    p1[0] = cvt_pk_bf16(br2.x, br2.y);
    p1[1] = cvt_pk_bf16(br2.z, br2.w);
    p1[2] = cvt_pk_bf16(br3.x, br3.y);
    p1[3] = cvt_pk_bf16(br3.z, br3.w);
    *(u32x4*)(sB + bldsoff) = p0;
    *(u32x4*)(sB + bldsoff + 16) = p1;
    __syncthreads();

    // ---- prefetch next K-step's B (latency hides under MFMA) ----
    if (k0 + 32 < 4096) {
      const float* ns = bsrc0 + k0 + 32;
      br0 = *(const float4*)(ns + 0);
      br1 = *(const float4*)(ns + 4);
      br2 = *(const float4*)(ns + 8);
      br3 = *(const float4*)(ns + 12);
    }

    u32x4 af[4], bf[4];
#pragma unroll
    for (int m = 0; m < 4; ++m)
      af[m] = *(const u32x4*)(sA + (wr * 64 + m * 16 + lr) * 64 + lk * 16);
#pragma unroll
    for (int n = 0; n < 4; ++n)
      bf[n] = *(const u32x4*)(sB + (wc * 64 + n * 16 + lr) * 64 + lk * 16);
#pragma unroll
    for (int m = 0; m < 4; ++m)
#pragma unroll
      for (int n = 0; n < 4; ++n)
        MFMA_BF16_16x16x32(acc[m][n], af[m], bf[n]);
    __syncthreads();
  }

  // C/D layout: col = lane&15, row = (lane>>4)*4 + j
#pragma unroll
  for (int m = 0; m < 4; ++m) {
    const int r0 = aRow0 + wr * 64 + m * 16 + lk * 4;
#pragma unroll
    for (int n = 0; n < 4; ++n) {
      const int col = bCol0 + wc * 64 + n * 16 + lr;
#pragma unroll
      for (int j = 0; j < 4; ++j)
        Ct[(size_t)(r0 + j) * 4096 + col] = f2bf_rne(acc[m][n][j]);
    }
  }
}

// ---------------------------------------------------------------------------
// K4: out[n, t*512 + r] = sum_d z[t,n,d] * dec[t,r,d] + bias[col]
// 128x64 tiles -> 8 t * 4 mb * 8 nb = 256 blocks (1/CU). 4 waves, 64x32 each.
// ---------------------------------------------------------------------------
__global__ __launch_bounds__(256, 2) void gemm_out_kernel(
    const u16* __restrict__ Z,    // [8][512][4096]
    const u16* __restrict__ Dec,  // [8][512][4096]
    const float* __restrict__ bias,
    float* __restrict__ out) {    // [512][4096]
  __shared__ char sA[8192];       // 128 x 32 bf16
  __shared__ char sB[4096];       // 64 x 32 bf16
  const int lb = blockIdx.x;
  const int swz = ((lb & 7) << 5) | (lb >> 3);  // 256 % 8 == 0
  const int t = swz >> 5;
  const int rem = swz & 31;
  const int nb = rem >> 2, mb = rem & 3;
  const u16* At = Z + ((size_t)t << 21);
  const u16* Bt = Dec + ((size_t)t << 21);
  const int aRow0 = mb << 7, bCol0 = nb << 6;
  const int tid = threadIdx.x;
  const int wv = tid >> 6, ln = tid & 63;
  const int lr = ln & 15, lk = ln >> 4;
  const int wr = wv >> 1, wc = wv & 1;

  fx4 acc[4][2] = {};

  const int rowS_l = ln >> 2;
  const int kkS = (ln & 3) * 8;

  for (int k0 = 0; k0 < 4096; k0 += 32) {
#pragma unroll
    for (int c = 0; c < 2; ++c) {
      const int seg = wv * 2 + c;
      const int row = seg * 16 + rowS_l;
      __builtin_amdgcn_global_load_lds(
          (gvoid*)(At + (size_t)(aRow0 + row) * 4096 + (k0 + kkS)),
          (lvoid*)(sA + seg * 1024 + ln * 16), 16, 0, 0);
    }
    {
      const int row = wv * 16 + rowS_l;
      __builtin_amdgcn_global_load_lds(
          (gvoid*)(Bt + (size_t)(bCol0 + row) * 4096 + (k0 + kkS)),
          (lvoid*)(sB + wv * 1024 + ln * 16), 16, 0, 0);
    }
    __syncthreads();

    u32x4 af[4], bf[2];
#pragma unroll
    for (int m = 0; m < 4; ++m)
      af[m] = *(const u32x4*)(sA + (wr * 64 + m * 16 + lr) * 64 + lk * 16);
#pragma unroll
    for (int n = 0; n < 2; ++n)
      bf[n] = *(const u32x4*)(sB + (wc * 32 + n * 16 + lr) * 64 + lk * 16);
#pragma unroll
    for (int m = 0; m < 4; ++m)
#pragma unroll
      for (int n = 0; n < 2; ++n)
        MFMA_BF16_16x16x32(acc[m][n], af[m], bf[n]);
    __syncthreads();
  }

#pragma unroll
  for (int n = 0; n < 2; ++n) {
    const int colg = (t << 9) + bCol0 + wc * 32 + n * 16 + lr;
    const float bv = bias[colg];
#pragma unroll
    for (int m = 0; m < 4; ++m) {
      const int r0 = aRow0 + wr * 64 + m * 16 + lk * 4;
#pragma unroll
      for (int j = 0; j < 4; ++j)
        out[(size_t)(r0 + j) * 4096 + colg] = acc[m][n][j] + bv;
    }
  }
}

// ---------------------------------------------------------------------------
extern "C" void kernel_launch(void* const* d_in, const int* in_sizes, int n_in,
                              void* d_out, int out_size, void* d_ws, size_t ws_size,
                              hipStream_t stream) {
  const float* x       = (const float*)d_in[0];   // [512][4096]
  const float* cw      = (const float*)d_in[1];   // [16384][4096]
  const int*   indices = (const int*)d_in[2];     // [8][512][4]
  const float* rot     = (const float*)d_in[3];   // [8][4096][4096]
  const float* scales  = (const float*)d_in[4];   // [8]
  const float* bias    = (const float*)d_in[5];   // [4096]
  float* out = (float*)d_out;
  char* ws = (char*)d_ws;

  u16* xb  = (u16*)(ws);                          // 4 MiB
  u16* dec = (u16*)(ws + ((size_t)4 << 20));      // 32 MiB
  u16* z   = (u16*)(ws + ((size_t)36 << 20));     // 32 MiB

  cvtx_kernel<<<dim3(2048), dim3(256), 0, stream>>>(x, xb);
  fused_z_decode_kernel<<<dim3(1280), dim3(256), 0, stream>>>(
      xb, rot, z, cw, indices, scales, dec);
  gemm_out_kernel<<<dim3(256), dim3(256), 0, stream>>>(z, dec, bias, out);
}

// Round 3
// 366.228 us; speedup vs baseline: 1.1315x; 1.1315x over previous
//
#include <hip/hip_runtime.h>

typedef unsigned int uint32;
typedef unsigned short u16;
typedef float fx4 __attribute__((ext_vector_type(4)));
typedef uint32 u32x4 __attribute__((ext_vector_type(4)));

typedef const __attribute__((address_space(1))) void gvoid;
typedef __attribute__((address_space(3))) void lvoid;

#define MFMA_BF16_16x16x32(acc, a, b) \
  asm("v_mfma_f32_16x16x32_bf16 %0, %1, %2, %0" : "+v"(acc) : "v"(a), "v"(b))

#define WAIT_LGKM0() asm volatile("s_waitcnt lgkmcnt(0)" ::: "memory")
#define WAIT_VM0()   asm volatile("s_waitcnt vmcnt(0)" ::: "memory")
#define WAIT_VM3()   asm volatile("s_waitcnt vmcnt(3)" ::: "memory")
#define SFENCE()     __builtin_amdgcn_sched_barrier(0)
#define BARRIER()    do { __builtin_amdgcn_s_barrier(); asm volatile("" ::: "memory"); } while (0)

__device__ __forceinline__ u16 f2bf_rne(float f) {
  uint32 u = __builtin_bit_cast(uint32, f);
  u += 0x7FFFu + ((u >> 16) & 1u);
  return (u16)(u >> 16);
}

__device__ __forceinline__ uint32 cvt_pk_bf16(float lo, float hi) {
  uint32 r;
  asm("v_cvt_pk_bf16_f32 %0, %1, %2" : "=v"(r) : "v"(lo), "v"(hi));
  return r;
}

// ---------------------------------------------------------------------------
// x (fp32) -> bf16
// ---------------------------------------------------------------------------
__global__ __launch_bounds__(256) void cvtx_kernel(const float* __restrict__ x,
                                                   u16* __restrict__ xb) {
  const int i = blockIdx.x * 256 + threadIdx.x;
  float4 v = ((const float4*)x)[i];
  ushort4 o;
  o.x = f2bf_rne(v.x);
  o.y = f2bf_rne(v.y);
  o.z = f2bf_rne(v.z);
  o.w = f2bf_rne(v.w);
  ((ushort4*)xb)[i] = o;
}

// ---------------------------------------------------------------------------
// decode body: dec[t,r,d] = scales[t]*0.25 * sum_k cw[idx[t,r,k], d] (bf16)
// ---------------------------------------------------------------------------
__device__ __forceinline__ void decode_body(
    int bid, const float* __restrict__ cw, const int* __restrict__ indices,
    const float* __restrict__ scales, u16* __restrict__ dec) {
  const int tid = threadIdx.x;
#pragma unroll 1
  for (int rr = 0; rr < 16; ++rr) {
    const int row = bid * 16 + rr;       // t*512 + r
    const int t = row >> 9;
    const int* ip = indices + (size_t)row * 4;
    const float* c0 = cw + (size_t)ip[0] * 4096;
    const float* c1 = cw + (size_t)ip[1] * 4096;
    const float* c2 = cw + (size_t)ip[2] * 4096;
    const float* c3 = cw + (size_t)ip[3] * 4096;
    const float s = scales[t] * 0.25f;
    u16* orow = dec + (size_t)row * 4096;
#pragma unroll
    for (int j = 0; j < 4; ++j) {
      const int d = j * 1024 + tid * 4;
      float4 a = *(const float4*)(c0 + d);
      float4 b = *(const float4*)(c1 + d);
      float4 c = *(const float4*)(c2 + d);
      float4 e = *(const float4*)(c3 + d);
      ushort4 o;
      o.x = f2bf_rne((a.x + b.x + c.x + e.x) * s);
      o.y = f2bf_rne((a.y + b.y + c.y + e.y) * s);
      o.z = f2bf_rne((a.z + b.z + c.z + e.z) * s);
      o.w = f2bf_rne((a.w + b.w + c.w + e.w) * s);
      *(ushort4*)(orow + d) = o;
    }
  }
}

// ---------------------------------------------------------------------------
// Fused: blocks [0,256) decode; blocks [256,1280) z[t] = x_bf16 @ rot[t]^T.
// GEMM: per-t M=512,N=4096,K=4096; 128x128 tile, BK=64, 4 waves.
// 2-phase raw-barrier pipeline (ONE s_barrier per K-step):
//   stage(t+1) issue -> ds_read frags(t) -> lgkm0+sched_fence -> 32 MFMA
//   -> vmcnt0 -> cvt+ds_write B(t+1) -> lgkm0 -> s_barrier
// LDS: per buffer, A and B each stored as two [128 rows][32k] bf16 sub-tiles
// (row=64B) so frag ds_reads are contiguous-1024B conflict-free, and
// global_load_lds destinations stay linear. 64 KB total, 2 blocks/CU.
// ---------------------------------------------------------------------------
__global__ __launch_bounds__(256, 2) void fused_z_decode_kernel(
    const u16* __restrict__ Xb,    // [512][4096] bf16
    const float* __restrict__ rot, // [8][4096][4096] fp32
    u16* __restrict__ Z,           // [8][512][4096] bf16
    const float* __restrict__ cw, const int* __restrict__ indices,
    const float* __restrict__ scales, u16* __restrict__ dec) {
  __shared__ char sA[32768];      // 2 bufs x (2 subtiles x [128][64B])
  __shared__ char sB[32768];

  const int bid = blockIdx.x;
  if (bid < 256) {
    decode_body(bid, cw, indices, scales, dec);
    return;
  }
  const int lb = bid - 256;
  const int swz = ((lb & 7) << 7) | (lb >> 3);  // XCD-chunked (1024 % 8 == 0)
  const int t = swz >> 7;
  const int rem = swz & 127;
  const int nb = rem >> 2, mb = rem & 3;        // mb-sharers of B-panel adjacent
  const float* Bt = rot + ((size_t)t << 24);
  u16* Ct = Z + ((size_t)t << 21);
  const int aRow0 = mb << 7, bCol0 = nb << 7;
  const int tid = threadIdx.x;
  const int wv = tid >> 6, ln = tid & 63;
  const int lr = ln & 15, lk = ln >> 4;
  const int wr = wv >> 1, wc = wv & 1;

  fx4 acc[4][4] = {};

  // A staging: 4 DMA/thread. dst o=c*4096+tid*16 -> q=c>>1,row=(c&1)*64+tid>>2,
  // k = q*32 + (tid&3)*8
  const u16* Asrc = Xb + (size_t)(aRow0 + (tid >> 2)) * 4096 + (tid & 3) * 8;
  // B staging (reg path): row=tid>>1, h=tid&1; fp32 k in [h*16,h*16+16)+q*32
  const float* Bsrc = Bt + (size_t)(bCol0 + (tid >> 1)) * 4096 + (tid & 1) * 16;
  const int bds = (tid >> 1) * 64 + (tid & 1) * 32;   // + q*8192 + j*16
  const int aof = (wr * 64 + lr) * 64 + lk * 16;      // + q*8192 + m*1024
  const int bof = (wc * 64 + lr) * 64 + lk * 16;

#define STAGE_A_Z(dbuf, kofs)                                                \
  _Pragma("unroll")                                                          \
  for (int c = 0; c < 4; ++c)                                                \
    __builtin_amdgcn_global_load_lds(                                        \
        (gvoid*)(Asrc + (size_t)((c & 1) << 6) * 4096 + ((c >> 1) << 5) +    \
                 (kofs)),                                                    \
        (lvoid*)(sA + (dbuf) * 16384 + c * 4096 + tid * 16), 16, 0, 0)

#define PACK_B_Z(dst)                                                        \
  do {                                                                       \
    u32x4 w_;                                                                \
    w_[0] = cvt_pk_bf16(q00.x, q00.y); w_[1] = cvt_pk_bf16(q00.z, q00.w);    \
    w_[2] = cvt_pk_bf16(q01.x, q01.y); w_[3] = cvt_pk_bf16(q01.z, q01.w);    \
    *(u32x4*)((dst) + bds) = w_;                                             \
    w_[0] = cvt_pk_bf16(q02.x, q02.y); w_[1] = cvt_pk_bf16(q02.z, q02.w);    \
    w_[2] = cvt_pk_bf16(q03.x, q03.y); w_[3] = cvt_pk_bf16(q03.z, q03.w);    \
    *(u32x4*)((dst) + bds + 16) = w_;                                        \
    w_[0] = cvt_pk_bf16(q10.x, q10.y); w_[1] = cvt_pk_bf16(q10.z, q10.w);    \
    w_[2] = cvt_pk_bf16(q11.x, q11.y); w_[3] = cvt_pk_bf16(q11.z, q11.w);    \
    *(u32x4*)((dst) + 8192 + bds) = w_;                                      \
    w_[0] = cvt_pk_bf16(q12.x, q12.y); w_[1] = cvt_pk_bf16(q12.z, q12.w);    \
    w_[2] = cvt_pk_bf16(q13.x, q13.y); w_[3] = cvt_pk_bf16(q13.z, q13.w);    \
    *(u32x4*)((dst) + 8192 + bds + 16) = w_;                                 \
  } while (0)

  // ---- prologue: stage kt=0 into buffer 0 ----
  {
    STAGE_A_Z(0, 0);
    float4 q00 = *(const float4*)(Bsrc + 0);
    float4 q01 = *(const float4*)(Bsrc + 4);
    float4 q02 = *(const float4*)(Bsrc + 8);
    float4 q03 = *(const float4*)(Bsrc + 12);
    float4 q10 = *(const float4*)(Bsrc + 32);
    float4 q11 = *(const float4*)(Bsrc + 36);
    float4 q12 = *(const float4*)(Bsrc + 40);
    float4 q13 = *(const float4*)(Bsrc + 44);
    WAIT_VM0();
    PACK_B_Z(sB);
    WAIT_LGKM0();
    BARRIER();
  }

  int d = 0;
#pragma unroll 1
  for (int kt = 0; kt < 64; ++kt) {
    float4 q00, q01, q02, q03, q10, q11, q12, q13;
    const bool last = (kt == 63);
    if (!last) {
      const int kn = (kt + 1) << 6;
      STAGE_A_Z(d ^ 1, kn);
      const float* bp = Bsrc + kn;
      q00 = *(const float4*)(bp + 0);
      q01 = *(const float4*)(bp + 4);
      q02 = *(const float4*)(bp + 8);
      q03 = *(const float4*)(bp + 12);
      q10 = *(const float4*)(bp + 32);
      q11 = *(const float4*)(bp + 36);
      q12 = *(const float4*)(bp + 40);
      q13 = *(const float4*)(bp + 44);
    }
    u32x4 af[2][4], bf[2][4];
    const char* pA = sA + d * 16384;
    const char* pB = sB + d * 16384;
#pragma unroll
    for (int q = 0; q < 2; ++q)
#pragma unroll
      for (int m = 0; m < 4; ++m) {
        af[q][m] = *(const u32x4*)(pA + q * 8192 + aof + m * 1024);
        bf[q][m] = *(const u32x4*)(pB + q * 8192 + bof + m * 1024);
      }
    WAIT_LGKM0();
    SFENCE();
    __builtin_amdgcn_s_setprio(1);
#pragma unroll
    for (int q = 0; q < 2; ++q)
#pragma unroll
      for (int m = 0; m < 4; ++m)
#pragma unroll
        for (int n = 0; n < 4; ++n)
          MFMA_BF16_16x16x32(acc[m][n], af[q][m], bf[q][n]);
    __builtin_amdgcn_s_setprio(0);
    SFENCE();
    if (!last) {
      WAIT_VM0();                 // A DMA (t+1) in LDS; B regs (t+1) arrived
      char* wB = sB + (d ^ 1) * 16384;
      PACK_B_Z(wB);
    }
    WAIT_LGKM0();                 // ds_writes visible
    BARRIER();
    d ^= 1;
  }

  // C/D layout: col = lane&15, row = (lane>>4)*4 + j
#pragma unroll
  for (int m = 0; m < 4; ++m) {
    const int r0 = aRow0 + wr * 64 + m * 16 + lk * 4;
#pragma unroll
    for (int n = 0; n < 4; ++n) {
      const int col = bCol0 + wc * 64 + n * 16 + lr;
#pragma unroll
      for (int j = 0; j < 4; ++j)
        Ct[(size_t)(r0 + j) * 4096 + col] = f2bf_rne(acc[m][n][j]);
    }
  }
#undef STAGE_A_Z
#undef PACK_B_Z
}

// ---------------------------------------------------------------------------
// out[n, t*512+r] = sum_d z[t,n,d]*dec[t,r,d] + bias. 128x64 tile, BK=32.
// Triple-buffered depth-2 pipeline, counted vmcnt(3) (3 DMA per stage):
// only 1 block/CU (grid=256), so two steps of compute hide the HBM latency.
// ---------------------------------------------------------------------------
__global__ __launch_bounds__(256, 2) void gemm_out_kernel(
    const u16* __restrict__ Z,    // [8][512][4096]
    const u16* __restrict__ Dec,  // [8][512][4096]
    const float* __restrict__ bias,
    float* __restrict__ out) {    // [512][4096]
  __shared__ char sm[36864];      // 3 bufs x (A 8KB + B 4KB)
  const int lb = blockIdx.x;
  const int swz = ((lb & 7) << 5) | (lb >> 3);  // 256 % 8 == 0
  const int t = swz >> 5;
  const int rem = swz & 31;
  const int nb = rem >> 2, mb = rem & 3;
  const u16* At = Z + ((size_t)t << 21);
  const u16* Bt = Dec + ((size_t)t << 21);
  const int aRow0 = mb << 7, bCol0 = nb << 6;
  const int tid = threadIdx.x;
  const int wv = tid >> 6, ln = tid & 63;
  const int lr = ln & 15, lk = ln >> 4;
  const int wr = wv >> 1, wc = wv & 1;

  fx4 acc[4][2] = {};

  // A: 2 DMA/thread: dst o=c*4096+tid*16 -> row=c*64+tid>>2, k=(tid&3)*8
  const u16* Asrc = At + (size_t)(aRow0 + (tid >> 2)) * 4096 + (tid & 3) * 8;
  // B: 1 DMA/thread: row=tid>>2 (64 rows), k=(tid&3)*8
  const u16* Bsrc = Bt + (size_t)(bCol0 + (tid >> 2)) * 4096 + (tid & 3) * 8;
  const int aof = (wr * 64 + lr) * 64 + lk * 16;   // + m*1024
  const int bof = 8192 + (wc * 32 + lr) * 64 + lk * 16;  // + n*1024

#define STAGE_O(buf, kofs)                                                   \
  do {                                                                       \
    _Pragma("unroll")                                                        \
    for (int c = 0; c < 2; ++c)                                              \
      __builtin_amdgcn_global_load_lds(                                      \
          (gvoid*)(Asrc + (size_t)(c << 6) * 4096 + (kofs)),                 \
          (lvoid*)((buf) + c * 4096 + tid * 16), 16, 0, 0);                  \
    __builtin_amdgcn_global_load_lds((gvoid*)(Bsrc + (kofs)),                \
                                     (lvoid*)((buf) + 8192 + tid * 16), 16,  \
                                     0, 0);                                  \
  } while (0)

  char* b0 = sm;
  char* b1 = sm + 12288;
  char* b2 = sm + 24576;
  STAGE_O(b0, 0);
  STAGE_O(b1, 32);
  WAIT_VM3();                     // first stage (3 ops) complete
  BARRIER();

#pragma unroll 1
  for (int kt = 0; kt < 128; ++kt) {
    if (kt + 2 < 128) STAGE_O(b2, (kt + 2) << 5);
    u32x4 af[4], bf[2];
#pragma unroll
    for (int m = 0; m < 4; ++m)
      af[m] = *(const u32x4*)(b0 + aof + m * 1024);
#pragma unroll
    for (int n = 0; n < 2; ++n)
      bf[n] = *(const u32x4*)(b0 + bof + n * 1024);
    WAIT_LGKM0();
    SFENCE();
#pragma unroll
    for (int m = 0; m < 4; ++m)
#pragma unroll
      for (int n = 0; n < 2; ++n)
        MFMA_BF16_16x16x32(acc[m][n], af[m], bf[n]);
    if (kt + 2 < 128) {
      WAIT_VM3();                 // oldest stage (t+1) complete
    } else {
      WAIT_VM0();
    }
    BARRIER();
    char* tmp = b0; b0 = b1; b1 = b2; b2 = tmp;
  }

#pragma unroll
  for (int n = 0; n < 2; ++n) {
    const int colg = (t << 9) + bCol0 + wc * 32 + n * 16 + lr;
    const float bv = bias[colg];
#pragma unroll
    for (int m = 0; m < 4; ++m) {
      const int r0 = aRow0 + wr * 64 + m * 16 + lk * 4;
#pragma unroll
      for (int j = 0; j < 4; ++j)
        out[(size_t)(r0 + j) * 4096 + colg] = acc[m][n][j] + bv;
    }
  }
#undef STAGE_O
}

// ---------------------------------------------------------------------------
extern "C" void kernel_launch(void* const* d_in, const int* in_sizes, int n_in,
                              void* d_out, int out_size, void* d_ws, size_t ws_size,
                              hipStream_t stream) {
  const float* x       = (const float*)d_in[0];   // [512][4096]
  const float* cw      = (const float*)d_in[1];   // [16384][4096]
  const int*   indices = (const int*)d_in[2];     // [8][512][4]
  const float* rot     = (const float*)d_in[3];   // [8][4096][4096]
  const float* scales  = (const float*)d_in[4];   // [8]
  const float* bias    = (const float*)d_in[5];   // [4096]
  float* out = (float*)d_out;
  char* ws = (char*)d_ws;

  u16* xb  = (u16*)(ws);                          // 4 MiB
  u16* dec = (u16*)(ws + ((size_t)4 << 20));      // 32 MiB
  u16* z   = (u16*)(ws + ((size_t)36 << 20));     // 32 MiB

  cvtx_kernel<<<dim3(2048), dim3(256), 0, stream>>>(x, xb);
  fused_z_decode_kernel<<<dim3(1280), dim3(256), 0, stream>>>(
      xb, rot, z, cw, indices, scales, dec);
  gemm_out_kernel<<<dim3(256), dim3(256), 0, stream>>>(z, dec, bias, out);
}

// Round 5
// 351.443 us; speedup vs baseline: 1.1791x; 1.0421x over previous
//
#include <hip/hip_runtime.h>

typedef unsigned int uint32;
typedef unsigned short u16;
typedef float fx4 __attribute__((ext_vector_type(4)));
typedef uint32 u32x4 __attribute__((ext_vector_type(4)));

typedef const __attribute__((address_space(1))) void gvoid;
typedef __attribute__((address_space(3))) void lvoid;

#define MFMA_BF16_16x16x32(acc, a, b) \
  asm("v_mfma_f32_16x16x32_bf16 %0, %1, %2, %0" : "+v"(acc) : "v"(a), "v"(b))

#define WAIT_LGKM0() asm volatile("s_waitcnt lgkmcnt(0)" ::: "memory")
#define WAIT_VM0()   asm volatile("s_waitcnt vmcnt(0)" ::: "memory")
#define WAIT_VM3()   asm volatile("s_waitcnt vmcnt(3)" ::: "memory")
#define WAIT_VM4()   asm volatile("s_waitcnt vmcnt(4)" ::: "memory")
#define WAIT_VM8()   asm volatile("s_waitcnt vmcnt(8)" ::: "memory")
#define WAIT_VM12()  asm volatile("s_waitcnt vmcnt(12)" ::: "memory")
#define SFENCE()     __builtin_amdgcn_sched_barrier(0)
#define BARRIER()    do { __builtin_amdgcn_s_barrier(); asm volatile("" ::: "memory"); } while (0)

__device__ __forceinline__ u16 f2bf_rne(float f) {
  uint32 u = __builtin_bit_cast(uint32, f);
  u += 0x7FFFu + ((u >> 16) & 1u);
  return (u16)(u >> 16);
}

__device__ __forceinline__ uint32 cvt_pk_bf16(float lo, float hi) {
  uint32 r;
  asm("v_cvt_pk_bf16_f32 %0, %1, %2" : "=v"(r) : "v"(lo), "v"(hi));
  return r;
}

// ---------------------------------------------------------------------------
// x (fp32) -> bf16
// ---------------------------------------------------------------------------
__global__ __launch_bounds__(256) void cvtx_kernel(const float* __restrict__ x,
                                                   u16* __restrict__ xb) {
  const int i = blockIdx.x * 256 + threadIdx.x;
  float4 v = ((const float4*)x)[i];
  ushort4 o;
  o.x = f2bf_rne(v.x);
  o.y = f2bf_rne(v.y);
  o.z = f2bf_rne(v.z);
  o.w = f2bf_rne(v.w);
  ((ushort4*)xb)[i] = o;
}

// ---------------------------------------------------------------------------
// decode body: dec[t,r,d] = scales[t]*0.25 * sum_k cw[idx[t,r,k], d] (bf16)
// ---------------------------------------------------------------------------
__device__ __forceinline__ void decode_body(
    int bid, const float* __restrict__ cw, const int* __restrict__ indices,
    const float* __restrict__ scales, u16* __restrict__ dec) {
  const int tid = threadIdx.x;
#pragma unroll 1
  for (int rr = 0; rr < 16; ++rr) {
    const int row = bid * 16 + rr;       // t*512 + r
    const int t = row >> 9;
    const int* ip = indices + (size_t)row * 4;
    const float* c0 = cw + (size_t)ip[0] * 4096;
    const float* c1 = cw + (size_t)ip[1] * 4096;
    const float* c2 = cw + (size_t)ip[2] * 4096;
    const float* c3 = cw + (size_t)ip[3] * 4096;
    const float s = scales[t] * 0.25f;
    u16* orow = dec + (size_t)row * 4096;
#pragma unroll
    for (int j = 0; j < 4; ++j) {
      const int d = j * 1024 + tid * 4;
      float4 a = *(const float4*)(c0 + d);
      float4 b = *(const float4*)(c1 + d);
      float4 c = *(const float4*)(c2 + d);
      float4 e = *(const float4*)(c3 + d);
      ushort4 o;
      o.x = f2bf_rne((a.x + b.x + c.x + e.x) * s);
      o.y = f2bf_rne((a.y + b.y + c.y + e.y) * s);
      o.z = f2bf_rne((a.z + b.z + c.z + e.z) * s);
      o.w = f2bf_rne((a.w + b.w + c.w + e.w) * s);
      *(ushort4*)(orow + d) = o;
    }
  }
}

// ---------------------------------------------------------------------------
// Fused: blocks [0,256) decode; blocks [256,1280) z[t] = x_bf16 @ rot[t]^T.
// GEMM: per-t M=512,N=4096,K=4096; 128x128 tile, BK=64, 4 waves.
// LDS layout (both tiles): subtile q (8KB) = [row][4 slots of 16B], where
// slot s holds k-chunk lk = s ^ ((row>>1)&3)  -> frag ds_read_b128 is
// conflict-free (2 lanes per bank-quad).
// A: global_load_lds with PRE-SWIZZLED SOURCE (chunk permute within 64B row,
// coalescing unchanged). B: reg-staged fp32 -> cvt_pk_bf16 -> swizzled
// ds_write. Depth-2 B prefetch, counted vmcnt (12/8) - never 0 in the loop.
// ---------------------------------------------------------------------------
__global__ __launch_bounds__(256, 2) void fused_z_decode_kernel(
    const u16* __restrict__ Xb,    // [512][4096] bf16
    const float* __restrict__ rot, // [8][4096][4096] fp32
    u16* __restrict__ Z,           // [8][512][4096] bf16
    const float* __restrict__ cw, const int* __restrict__ indices,
    const float* __restrict__ scales, u16* __restrict__ dec) {
  __shared__ char sA[32768];      // 2 bufs x 2 subtiles x [128][64B]
  __shared__ char sB[32768];

  const int bid = blockIdx.x;
  if (bid < 256) {
    decode_body(bid, cw, indices, scales, dec);
    return;
  }
  const int lb = bid - 256;
  const int swz = ((lb & 7) << 7) | (lb >> 3);  // XCD-chunked (1024 % 8 == 0)
  const int t = swz >> 7;
  const int rem = swz & 127;
  const int nb = rem >> 2, mb = rem & 3;        // mb-sharers of B-panel adjacent
  const float* Bt = rot + ((size_t)t << 24);
  u16* Ct = Z + ((size_t)t << 21);
  const int aRow0 = mb << 7, bCol0 = nb << 7;
  const int tid = threadIdx.x;
  const int wv = tid >> 6, ln = tid & 63;
  const int lr = ln & 15, lk = ln >> 4;
  const int wr = wv >> 1, wc = wv & 1;

  fx4 acc[4][4] = {};

  // ---- A staging: source pre-swizzle (16B chunk permute within 64B row)
  const u16* Asrc = Xb + (size_t)(aRow0 + (ln >> 2)) * 4096 +
                    (((ln & 3) ^ ((ln >> 3) & 3)) << 3);
  // ---- B staging (reg): row = tid>>1, k-half h = tid&1
  const float* Bsrc = Bt + (size_t)(bCol0 + (tid >> 1)) * 4096 + (tid & 1) * 16;
  const int bds = (tid >> 1) * 64 + ((((tid & 1) << 1) ^ ((tid >> 2) & 3)) << 4);
  // ---- frag read offsets: slot-XOR folded into per-lane constant
  const int gr = (lr >> 1) & 3;
  const int aof = (wr * 64 + lr) * 64 + ((lk ^ gr) << 4);  // + q*8192 + m*1024
  const int bof = (wc * 64 + lr) * 64 + ((lk ^ gr) << 4);

#define STAGE_A_Z(dbuf, kofs)                                                 \
  _Pragma("unroll")                                                           \
  for (int c = 0; c < 4; ++c)                                                 \
    __builtin_amdgcn_global_load_lds(                                         \
        (gvoid*)(Asrc + (size_t)(((c & 1) * 4 + wv) << 4) * 4096 +            \
                 ((c >> 1) << 5) + (kofs)),                                   \
        (lvoid*)(sA + (dbuf) * 16384 + ((c >> 1) << 13) +                     \
                 (((c & 1) * 4 + wv) << 10) + ln * 16), 16, 0, 0)

#define LOADB(p, kofs)                                                        \
  do {                                                                        \
    const float* bp_ = Bsrc + (kofs);                                         \
    p[0] = *(const float4*)(bp_ + 0);                                         \
    p[1] = *(const float4*)(bp_ + 4);                                         \
    p[2] = *(const float4*)(bp_ + 8);                                         \
    p[3] = *(const float4*)(bp_ + 12);                                        \
    p[4] = *(const float4*)(bp_ + 32);                                        \
    p[5] = *(const float4*)(bp_ + 36);                                        \
    p[6] = *(const float4*)(bp_ + 40);                                        \
    p[7] = *(const float4*)(bp_ + 44);                                        \
  } while (0)

#define PACK_B(p, dst)                                                        \
  do {                                                                        \
    u32x4 w_;                                                                 \
    w_[0] = cvt_pk_bf16(p[0].x, p[0].y); w_[1] = cvt_pk_bf16(p[0].z, p[0].w); \
    w_[2] = cvt_pk_bf16(p[1].x, p[1].y); w_[3] = cvt_pk_bf16(p[1].z, p[1].w); \
    *(u32x4*)((dst) + bds) = w_;                                              \
    w_[0] = cvt_pk_bf16(p[2].x, p[2].y); w_[1] = cvt_pk_bf16(p[2].z, p[2].w); \
    w_[2] = cvt_pk_bf16(p[3].x, p[3].y); w_[3] = cvt_pk_bf16(p[3].z, p[3].w); \
    *(u32x4*)((dst) + (bds ^ 16)) = w_;                                       \
    w_[0] = cvt_pk_bf16(p[4].x, p[4].y); w_[1] = cvt_pk_bf16(p[4].z, p[4].w); \
    w_[2] = cvt_pk_bf16(p[5].x, p[5].y); w_[3] = cvt_pk_bf16(p[5].z, p[5].w); \
    *(u32x4*)((dst) + 8192 + bds) = w_;                                       \
    w_[0] = cvt_pk_bf16(p[6].x, p[6].y); w_[1] = cvt_pk_bf16(p[6].z, p[6].w); \
    w_[2] = cvt_pk_bf16(p[7].x, p[7].y); w_[3] = cvt_pk_bf16(p[7].z, p[7].w); \
    *(u32x4*)((dst) + 8192 + (bds ^ 16)) = w_;                                \
  } while (0)

#define COMPUTE(dIdx)                                                         \
  do {                                                                        \
    const char* pA_ = sA + (dIdx) * 16384;                                    \
    const char* pB_ = sB + (dIdx) * 16384;                                    \
    u32x4 af[2][4], bf[2][4];                                                 \
    _Pragma("unroll")                                                         \
    for (int q = 0; q < 2; ++q)                                               \
      _Pragma("unroll")                                                       \
      for (int m = 0; m < 4; ++m) {                                           \
        af[q][m] = *(const u32x4*)(pA_ + q * 8192 + aof + m * 1024);          \
        bf[q][m] = *(const u32x4*)(pB_ + q * 8192 + bof + m * 1024);          \
      }                                                                       \
    WAIT_LGKM0();                                                             \
    SFENCE();                                                                 \
    __builtin_amdgcn_s_setprio(1);                                            \
    _Pragma("unroll")                                                         \
    for (int q = 0; q < 2; ++q)                                               \
      _Pragma("unroll")                                                       \
      for (int m = 0; m < 4; ++m)                                             \
        _Pragma("unroll")                                                     \
        for (int n = 0; n < 4; ++n)                                           \
          MFMA_BF16_16x16x32(acc[m][n], af[q][m], bf[q][n]);                  \
    __builtin_amdgcn_s_setprio(0);                                            \
    SFENCE();                                                                 \
  } while (0)

  float4 pa[8], pb[8];

  // ---- prologue: A(0)->buf0, B(0)->pa->pack->buf0, B(1)->pb in flight ----
  STAGE_A_Z(0, 0);
  LOADB(pa, 0);
  WAIT_VM0();
  PACK_B(pa, sB);
  LOADB(pb, 64);                  // 8 outstanding across the barrier
  WAIT_LGKM0();
  BARRIER();

#pragma unroll 1
  for (int kt2 = 0; kt2 < 64; kt2 += 2) {
    const bool more = (kt2 < 62);
    // ---- even kt = kt2: read buf0; A(kt+1)->buf1; load pa = B(kt+2) ----
    STAGE_A_Z(1, (kt2 + 1) << 6);
    if (more) LOADB(pa, (kt2 + 2) << 6);
    COMPUTE(0);
    if (more) {
      WAIT_VM12();                // pb = B(kt2+1) regs ready (12 newer in flight)
      PACK_B(pb, sB + 16384);
      WAIT_VM8();                 // A(kt2+1) DMA done; B(kt2+2) stays in flight
    } else {
      WAIT_VM4();
      PACK_B(pb, sB + 16384);
      WAIT_VM0();
    }
    WAIT_LGKM0();
    BARRIER();
    // ---- odd kt = kt2+1: read buf1; A(kt+1)->buf0; load pb = B(kt+2) ----
    if (more) {
      STAGE_A_Z(0, (kt2 + 2) << 6);
      LOADB(pb, (kt2 + 3) << 6);
    }
    COMPUTE(1);
    if (more) {
      WAIT_VM12();                // pa = B(kt2+2) regs ready
      PACK_B(pa, sB);
      WAIT_VM8();
      WAIT_LGKM0();
      BARRIER();
    }
  }

  // C/D layout: col = lane&15, row = (lane>>4)*4 + j
#pragma unroll
  for (int m = 0; m < 4; ++m) {
    const int r0 = aRow0 + wr * 64 + m * 16 + lk * 4;
#pragma unroll
    for (int n = 0; n < 4; ++n) {
      const int col = bCol0 + wc * 64 + n * 16 + lr;
#pragma unroll
      for (int j = 0; j < 4; ++j)
        Ct[(size_t)(r0 + j) * 4096 + col] = f2bf_rne(acc[m][n][j]);
    }
  }
#undef STAGE_A_Z
#undef LOADB
#undef PACK_B
#undef COMPUTE
}

// ---------------------------------------------------------------------------
// out[n, t*512+r] = sum_d z[t,n,d]*dec[t,r,d] + bias. 128x64 tile, BK=32.
// Triple-buffered depth-2 pipeline, counted vmcnt(3). Same slot-XOR swizzle
// (source-side for global_load_lds, per-lane constant on frag reads).
// ---------------------------------------------------------------------------
__global__ __launch_bounds__(256, 2) void gemm_out_kernel(
    const u16* __restrict__ Z,    // [8][512][4096]
    const u16* __restrict__ Dec,  // [8][512][4096]
    const float* __restrict__ bias,
    float* __restrict__ out) {    // [512][4096]
  __shared__ char sm[36864];      // 3 bufs x (A 8KB + B 4KB)
  const int lb = blockIdx.x;
  const int swz = ((lb & 7) << 5) | (lb >> 3);  // 256 % 8 == 0
  const int t = swz >> 5;
  const int rem = swz & 31;
  const int nb = rem >> 2, mb = rem & 3;
  const u16* At = Z + ((size_t)t << 21);
  const u16* Bt = Dec + ((size_t)t << 21);
  const int aRow0 = mb << 7, bCol0 = nb << 6;
  const int tid = threadIdx.x;
  const int wv = tid >> 6, ln = tid & 63;
  const int lr = ln & 15, lk = ln >> 4;
  const int wr = wv >> 1, wc = wv & 1;

  fx4 acc[4][2] = {};

  const int kswz = (((tid & 3) ^ ((tid >> 3) & 3)) << 3);
  const u16* Asrc = At + (size_t)(aRow0 + (tid >> 2)) * 4096 + kswz;
  const u16* Bsrc = Bt + (size_t)(bCol0 + (tid >> 2)) * 4096 + kswz;
  const int gr = (lr >> 1) & 3;
  const int aof = (wr * 64 + lr) * 64 + ((lk ^ gr) << 4);          // + m*1024
  const int bof = 8192 + (wc * 32 + lr) * 64 + ((lk ^ gr) << 4);   // + n*1024

#define STAGE_O(buf, kofs)                                                   \
  do {                                                                       \
    _Pragma("unroll")                                                        \
    for (int c = 0; c < 2; ++c)                                              \
      __builtin_amdgcn_global_load_lds(                                      \
          (gvoid*)(Asrc + (size_t)(c << 6) * 4096 + (kofs)),                 \
          (lvoid*)((buf) + c * 4096 + tid * 16), 16, 0, 0);                  \
    __builtin_amdgcn_global_load_lds((gvoid*)(Bsrc + (kofs)),                \
                                     (lvoid*)((buf) + 8192 + tid * 16), 16,  \
                                     0, 0);                                  \
  } while (0)

  char* b0 = sm;
  char* b1 = sm + 12288;
  char* b2 = sm + 24576;
  STAGE_O(b0, 0);
  STAGE_O(b1, 32);
  WAIT_VM3();                     // first stage (3 ops) complete
  BARRIER();

#pragma unroll 1
  for (int kt = 0; kt < 128; ++kt) {
    if (kt + 2 < 128) STAGE_O(b2, (kt + 2) << 5);
    u32x4 af[4], bf[2];
#pragma unroll
    for (int m = 0; m < 4; ++m)
      af[m] = *(const u32x4*)(b0 + aof + m * 1024);
#pragma unroll
    for (int n = 0; n < 2; ++n)
      bf[n] = *(const u32x4*)(b0 + bof + n * 1024);
    WAIT_LGKM0();
    SFENCE();
#pragma unroll
    for (int m = 0; m < 4; ++m)
#pragma unroll
      for (int n = 0; n < 2; ++n)
        MFMA_BF16_16x16x32(acc[m][n], af[m], bf[n]);
    if (kt + 2 < 128) {
      WAIT_VM3();                 // oldest stage (kt+1's buffer) complete
    } else {
      WAIT_VM0();
    }
    BARRIER();
    char* tmp = b0; b0 = b1; b1 = b2; b2 = tmp;
  }

#pragma unroll
  for (int n = 0; n < 2; ++n) {
    const int colg = (t << 9) + bCol0 + wc * 32 + n * 16 + lr;
    const float bv = bias[colg];
#pragma unroll
    for (int m = 0; m < 4; ++m) {
      const int r0 = aRow0 + wr * 64 + m * 16 + lk * 4;
#pragma unroll
      for (int j = 0; j < 4; ++j)
        out[(size_t)(r0 + j) * 4096 + colg] = acc[m][n][j] + bv;
    }
  }
#undef STAGE_O
}

// ---------------------------------------------------------------------------
extern "C" void kernel_launch(void* const* d_in, const int* in_sizes, int n_in,
                              void* d_out, int out_size, void* d_ws, size_t ws_size,
                              hipStream_t stream) {
  const float* x       = (const float*)d_in[0];   // [512][4096]
  const float* cw      = (const float*)d_in[1];   // [16384][4096]
  const int*   indices = (const int*)d_in[2];     // [8][512][4]
  const float* rot     = (const float*)d_in[3];   // [8][4096][4096]
  const float* scales  = (const float*)d_in[4];   // [8]
  const float* bias    = (const float*)d_in[5];   // [4096]
  float* out = (float*)d_out;
  char* ws = (char*)d_ws;

  u16* xb  = (u16*)(ws);                          // 4 MiB
  u16* dec = (u16*)(ws + ((size_t)4 << 20));      // 32 MiB
  u16* z   = (u16*)(ws + ((size_t)36 << 20));     // 32 MiB

  cvtx_kernel<<<dim3(2048), dim3(256), 0, stream>>>(x, xb);
  fused_z_decode_kernel<<<dim3(1280), dim3(256), 0, stream>>>(
      xb, rot, z, cw, indices, scales, dec);
  gemm_out_kernel<<<dim3(256), dim3(256), 0, stream>>>(z, dec, bias, out);
}